// Round 8
// baseline (458.639 us; speedup 1.0000x reference)
//
#include <hip/hip_runtime.h>
#include <hip/hip_bf16.h>

#define NHEADS 16
#define HDIM   64
#define HID    1024
#define BB     4
#define SS     4096
#define MM     (BB*SS)      // 16384 rows
#define KK     HID          // 1024
#define NN     (2*HID)      // 2048 cols (Q | K)

using short8 = __attribute__((ext_vector_type(8))) short;
using f32x4  = __attribute__((ext_vector_type(4))) float;

__device__ __forceinline__ float bf2f(ushort u) {
  return __uint_as_float(((unsigned)u) << 16);
}
__device__ __forceinline__ ushort f2bf(float f) {
  unsigned u = __float_as_uint(f);
  unsigned r = (u + 0x7fffu + ((u >> 16) & 1u)) >> 16;  // RNE
  return (ushort)r;
}

__device__ __forceinline__ void gload16(const void* g, void* l) {
  __builtin_amdgcn_global_load_lds(
      (const __attribute__((address_space(1))) void*)g,
      (__attribute__((address_space(3))) void*)l, 16, 0, 0);
}

// ---------------------------------------------------------------- cast hs->bf16
__global__ __launch_bounds__(256) void cast_hs_k(const float* __restrict__ in,
                                                 ushort* __restrict__ out) {
  size_t i = ((size_t)blockIdx.x * 256 + threadIdx.x) * 8;
  float4 a = *(const float4*)(in + i);
  float4 b = *(const float4*)(in + i + 4);
  ushort r[8];
  r[0]=f2bf(a.x); r[1]=f2bf(a.y); r[2]=f2bf(a.z); r[3]=f2bf(a.w);
  r[4]=f2bf(b.x); r[5]=f2bf(b.y); r[6]=f2bf(b.z); r[7]=f2bf(b.w);
  *(uint4*)(out + i) = *(const uint4*)r;
}

// ------------------------------------------- W (K,N) -> Bt (N,K) bf16, Wq|Wkv fused
__global__ __launch_bounds__(256) void wcast_k(const float* __restrict__ Wq,
                                               const float* __restrict__ Wkv,
                                               ushort* __restrict__ Bt) {
  __shared__ float tile[32][33];
  int k0 = blockIdx.x * 32, n0 = blockIdx.y * 32;
  int tx = threadIdx.x, ty = threadIdx.y;
  const float* src = (n0 < HID) ? Wq : Wkv;
  int nc = (n0 < HID) ? n0 : n0 - HID;
#pragma unroll
  for (int j = 0; j < 4; ++j)
    tile[ty + 8*j][tx] = src[(size_t)(k0 + ty + 8*j) * HID + nc + tx];
  __syncthreads();
#pragma unroll
  for (int j = 0; j < 4; ++j)
    Bt[(size_t)(n0 + ty + 8*j) * KK + k0 + tx] = f2bf(tile[tx][ty + 8*j]);
}

// =======================================================================
// Shared GEMM geometry macros (R5 structure)
// LDS byte map: A0K0=0 A0K1=16384 B0K0=32768 B0K1=49152
//               A1K0=65536 A1K1=81920 B1K0=98304 B1K1=114688
// =======================================================================
#define GEMM_SETUP(NBLK_SHIFT)                                                  \
  extern __shared__ char lds_c[];                                               \
  const int tid = threadIdx.x;                                                  \
  const int bid = blockIdx.x;                                                   \
  const int wg = (bid & 7) * (1 << (NBLK_SHIFT)) + (bid >> 3);                  \
  const int tm = wg >> 3, tn = wg & 7;                                          \
  const int w = tid >> 6, lane = tid & 63;                                      \
  const int wr = w >> 2, wc = w & 3;                                            \
  const int lr = lane & 15, hi = lane >> 4;                                     \
  const ushort* Ab = A + (size_t)tm * 256 * KK;                                 \
  const ushort* Bb = Bt + (size_t)tn * 256 * KK;                                \
  const int d0 = tid * 16;                                                      \
  const int gch = (tid & 3) ^ ((tid >> 3) & 3);                                 \
  const size_t soff0 = (size_t)(tid >> 2) * KK + gch * 8;                       \
  const size_t soff1 = soff0 + (size_t)128 * KK;                                \
  const int swz = (hi ^ ((lr >> 1) & 3)) << 4;                                  \
  const int arow = (wr * 128 + lr) * 64 + swz;                                  \
  const int brow = (wc * 64 + lr) * 64 + swz;

#define STG(PANEL, KOFF, DSTB)                                                  \
  {                                                                             \
    const ushort* g_ = (PANEL) + (KOFF);                                        \
    gload16(g_ + soff0, lds_c + (DSTB) + d0);                                   \
    gload16(g_ + soff1, lds_c + (DSTB) + 8192 + d0);                            \
  }

#define WAITV(N)                                                                \
  { asm volatile("s_waitcnt vmcnt(" #N ")" ::: "memory");                       \
    __builtin_amdgcn_sched_barrier(0); }

// ---------------------------------------------------------------- real GEMM (R5)
__global__ __launch_bounds__(512, 2) void gemm_k(const ushort* __restrict__ A,
                                                 const ushort* __restrict__ Bt,
                                                 const float* __restrict__ bq,
                                                 const float* __restrict__ bkv,
                                                 ushort* __restrict__ C) {
  GEMM_SETUP(6)   // 512 blocks -> chunk 64 per XCD

  f32x4 acc[8][4];
#pragma unroll
  for (int M = 0; M < 8; ++M)
#pragma unroll
    for (int n = 0; n < 4; ++n) acc[M][n] = (f32x4){0.f, 0.f, 0.f, 0.f};
  short8 bfrag[4];

#define LOADB(BBASE)                                                            \
  _Pragma("unroll") for (int n = 0; n < 4; ++n)                                 \
    bfrag[n] = *(const short8*)(lds_c + (BBASE) + n * 1024 + brow);

#define PH(ABASE, MH, STAGE_CODE, TAIL_CODE)                                    \
  {                                                                             \
    short8 afrag[4];                                                            \
    _Pragma("unroll") for (int m = 0; m < 4; ++m)                               \
      afrag[m] = *(const short8*)(lds_c + (ABASE) + (MH) * 4096 +               \
                                  m * 1024 + arow);                             \
    STAGE_CODE;                                                                 \
    __builtin_amdgcn_s_barrier();                                               \
    __builtin_amdgcn_sched_barrier(0);                                          \
    __builtin_amdgcn_s_setprio(1);                                              \
    _Pragma("unroll") for (int m = 0; m < 4; ++m)                               \
      _Pragma("unroll") for (int n = 0; n < 4; ++n)                             \
        acc[(MH) * 4 + m][n] = __builtin_amdgcn_mfma_f32_16x16x32_bf16(         \
            bfrag[n], afrag[m], acc[(MH) * 4 + m][n], 0, 0, 0);                 \
    __builtin_amdgcn_s_setprio(0);                                              \
    TAIL_CODE;                                                                  \
    __builtin_amdgcn_s_barrier();                                               \
    asm volatile("" ::: "memory");                                              \
  }

  STG(Bb, 0,   32768);
  STG(Ab, 0,   0);
  STG(Bb, 32,  49152);
  STG(Ab, 32,  16384);
  STG(Bb, 64,  98304);
  STG(Ab, 64,  65536);
  WAITV(8)
  __builtin_amdgcn_s_barrier();
  asm volatile("" ::: "memory");

#pragma unroll 1
  for (int it = 0; it < 7; ++it) {
    LOADB(32768)
    PH(0, 0, STG(Bb, (2 * it + 1) * 64 + 32, 114688), {})
    PH(0, 1, STG(Ab, (2 * it + 1) * 64 + 32, 81920), WAITV(8))
    LOADB(49152)
    PH(16384, 0, STG(Bb, (2 * it + 2) * 64, 32768), {})
    PH(16384, 1, STG(Ab, (2 * it + 2) * 64, 0), WAITV(8))
    LOADB(98304)
    PH(65536, 0, STG(Bb, (2 * it + 2) * 64 + 32, 49152), {})
    PH(65536, 1, STG(Ab, (2 * it + 2) * 64 + 32, 16384), WAITV(8))
    LOADB(114688)
    PH(81920, 0, STG(Bb, (2 * it + 3) * 64, 98304), {})
    PH(81920, 1, STG(Ab, (2 * it + 3) * 64, 65536), WAITV(8))
  }
  LOADB(32768)
  PH(0, 0, STG(Bb, 15 * 64 + 32, 114688), {})
  PH(0, 1, STG(Ab, 15 * 64 + 32, 81920), WAITV(8))
  LOADB(49152)
  PH(16384, 0, {}, {})
  PH(16384, 1, {}, WAITV(4))
  LOADB(98304)
  PH(65536, 0, {}, {})
  PH(65536, 1, {}, WAITV(0))
  LOADB(114688)
  PH(81920, 0, {}, {})
  PH(81920, 1, {}, {})

#undef PH
#undef LOADB

  const float* bias = (tn < 4) ? (bq + tn * 256) : (bkv + (tn - 4) * 256);
  float4 bv[4];
#pragma unroll
  for (int n = 0; n < 4; ++n)
    bv[n] = *(const float4*)(bias + wc * 64 + n * 16 + hi * 4);

#pragma unroll
  for (int M = 0; M < 8; ++M) {
    size_t row = (size_t)tm * 256 + wr * 128 + M * 16 + lr;
    ushort* cp = C + row * NN + tn * 256 + wc * 64 + hi * 4;
#pragma unroll
    for (int n = 0; n < 4; ++n) {
      unsigned p0 = (unsigned)f2bf(acc[M][n][0] + bv[n].x) |
                    ((unsigned)f2bf(acc[M][n][1] + bv[n].y) << 16);
      unsigned p1 = (unsigned)f2bf(acc[M][n][2] + bv[n].z) |
                    ((unsigned)f2bf(acc[M][n][3] + bv[n].w) << 16);
      uint2 st; st.x = p0; st.y = p1;
      *(uint2*)(cp + n * 16) = st;
    }
  }
}

// ----------------------------------------------- GEMM ablation variants (diag)
// 256-block grid, REPS passes over the K loop (tile idx wraps &15). Writes into
// QK rows [0,8192) -- fully overwritten by the real gemm_k afterwards.
// NOSTG: remove in-loop staging + vmcnt.  NODS: remove per-phase ds_reads
// (fragments fixed from prologue).  Barriers + setprio + MFMA always kept.
// REPS sized so each dispatch exceeds gemm_k's ~86us and surfaces in top-5.
template<int NOSTG, int NODS, int REPS>
__global__ __launch_bounds__(512, 2) void gemm_abl(const ushort* __restrict__ A,
                                                   const ushort* __restrict__ Bt,
                                                   ushort* __restrict__ C) {
  GEMM_SETUP(5)   // 256 blocks -> chunk 32 per XCD

  f32x4 acc[8][4];
#pragma unroll
  for (int M = 0; M < 8; ++M)
#pragma unroll
    for (int n = 0; n < 4; ++n) acc[M][n] = (f32x4){0.f, 0.f, 0.f, 0.f};
  short8 bfrag[4], afrag[4];

#define LOADB(BBASE)                                                            \
  if constexpr (!NODS) {                                                        \
    _Pragma("unroll") for (int n = 0; n < 4; ++n)                               \
      bfrag[n] = *(const short8*)(lds_c + (BBASE) + n * 1024 + brow);           \
  }

#define PH(ABASE, MH, STAGE_CODE, TAIL_CODE)                                    \
  {                                                                             \
    if constexpr (!NODS) {                                                      \
      _Pragma("unroll") for (int m = 0; m < 4; ++m)                             \
        afrag[m] = *(const short8*)(lds_c + (ABASE) + (MH) * 4096 +             \
                                    m * 1024 + arow);                           \
    }                                                                           \
    if constexpr (!NOSTG) { STAGE_CODE; }                                       \
    __builtin_amdgcn_s_barrier();                                               \
    __builtin_amdgcn_sched_barrier(0);                                          \
    __builtin_amdgcn_s_setprio(1);                                              \
    _Pragma("unroll") for (int m = 0; m < 4; ++m)                               \
      _Pragma("unroll") for (int n = 0; n < 4; ++n)                             \
        acc[(MH) * 4 + m][n] = __builtin_amdgcn_mfma_f32_16x16x32_bf16(         \
            bfrag[n], afrag[m], acc[(MH) * 4 + m][n], 0, 0, 0);                 \
    __builtin_amdgcn_s_setprio(0);                                              \
    if constexpr (!NOSTG) { TAIL_CODE; }                                        \
    __builtin_amdgcn_s_barrier();                                               \
    asm volatile("" ::: "memory");                                              \
  }

  // prologue (identical across variants): 12 loads, retire first 4
  STG(Bb, 0,   32768);
  STG(Ab, 0,   0);
  STG(Bb, 32,  49152);
  STG(Ab, 32,  16384);
  STG(Bb, 64,  98304);
  STG(Ab, 64,  65536);
  WAITV(8)
  __builtin_amdgcn_s_barrier();
  asm volatile("" ::: "memory");
  if constexpr (NODS) {   // fix fragments once (real tile0 data)
#pragma unroll
    for (int n = 0; n < 4; ++n)
      bfrag[n] = *(const short8*)(lds_c + 32768 + n * 1024 + brow);
#pragma unroll
    for (int m = 0; m < 4; ++m)
      afrag[m] = *(const short8*)(lds_c + m * 1024 + arow);
  }

#pragma unroll 1
  for (int rep = 0; rep < REPS; ++rep) {
#pragma unroll 1
    for (int it = 0; it < 8; ++it) {
      const int t1 = (2 * it + 1) & 15, t2 = (2 * it + 2) & 15,
                t3 = (2 * it + 3) & 15;
      LOADB(32768)
      PH(0, 0, STG(Bb, t1 * 64 + 32, 114688), {})
      PH(0, 1, STG(Ab, t1 * 64 + 32, 81920), WAITV(8))
      LOADB(49152)
      PH(16384, 0, STG(Bb, t2 * 64, 32768), {})
      PH(16384, 1, STG(Ab, t2 * 64, 0), WAITV(8))
      LOADB(98304)
      PH(65536, 0, STG(Bb, t2 * 64 + 32, 49152), {})
      PH(65536, 1, STG(Ab, t2 * 64 + 32, 16384), WAITV(8))
      LOADB(114688)
      PH(81920, 0, STG(Bb, t3 * 64, 98304), {})
      PH(81920, 1, STG(Ab, t3 * 64, 65536), WAITV(8))
    }
  }
  WAITV(0)

#undef PH
#undef LOADB

#pragma unroll
  for (int M = 0; M < 8; ++M) {
    size_t row = (size_t)tm * 256 + wr * 128 + M * 16 + lr;
    ushort* cp = C + row * NN + tn * 256 + wc * 64 + hi * 4;
#pragma unroll
    for (int n = 0; n < 4; ++n) {
      unsigned p0 = (unsigned)f2bf(acc[M][n][0]) |
                    ((unsigned)f2bf(acc[M][n][1]) << 16);
      unsigned p1 = (unsigned)f2bf(acc[M][n][2]) |
                    ((unsigned)f2bf(acc[M][n][3]) << 16);
      uint2 st; st.x = p0; st.y = p1;
      *(uint2*)(cp + n * 16) = st;
    }
  }
}

// ------------------------------------------------- global attention, split-K flash
#define GCH 8
#define GCS (SS / GCH)  // 512

__global__ __launch_bounds__(512) void gattn_part_k(const ushort* __restrict__ QK,
                                                    const float* __restrict__ mask,
                                                    float* __restrict__ P) {
  const int bh = blockIdx.x >> 3, c = blockIdx.x & 7;
  const int b = bh >> 4, h = bh & 15;
  const int tid = threadIdx.x, w = tid >> 6, lane = tid & 63;
  __shared__ float sc[GCS];
  __shared__ float red[8];
  __shared__ float vacc[8][64];

  const float gq = bf2f(QK[(size_t)b * SS * NN + h * HDIM + lane]);  // Q row s=0
  const int s0 = c * GCS;
  float mx = -1e30f;
  for (int s = w; s < GCS; s += 8) {
    float kv = bf2f(QK[((size_t)b * SS + s0 + s) * NN + HID + h * HDIM + lane]);
    float p = gq * kv;
#pragma unroll
    for (int o = 32; o; o >>= 1) p += __shfl_xor(p, o, 64);
    p = p * 0.125f + mask[b * SS + s0 + s];
    if (lane == 0) sc[s] = p;
    mx = fmaxf(mx, p);
  }
  if (lane == 0) red[w] = mx;
  __syncthreads();
  float bm = -1e30f;
#pragma unroll
  for (int i = 0; i < 8; ++i) bm = fmaxf(bm, red[i]);
  __syncthreads();
  float ls = 0.f;
  for (int s = tid; s < GCS; s += 512) {
    float e = __expf(sc[s] - bm);
    sc[s] = e;
    ls += e;
  }
#pragma unroll
  for (int o = 32; o; o >>= 1) ls += __shfl_xor(ls, o, 64);
  if (lane == 0) red[w] = ls;
  __syncthreads();
  float tot = 0.f;
#pragma unroll
  for (int i = 0; i < 8; ++i) tot += red[i];

  float a = 0.f;
  for (int s = w; s < GCS; s += 8)
    a += sc[s] * bf2f(QK[((size_t)b * SS + s0 + s) * NN + HID + h * HDIM + lane]);
  vacc[w][lane] = a;
  __syncthreads();
  if (w == 0) {
    float v = 0.f;
#pragma unroll
    for (int i = 0; i < 8; ++i) v += vacc[i][lane];
    P[1024 + (bh * 8 + c) * 64 + lane] = v;
    if (lane == 0) {
      P[bh * 8 + c] = bm;
      P[512 + bh * 8 + c] = tot;
    }
  }
}

__global__ __launch_bounds__(64) void gattn_comb_k(const float* __restrict__ P,
                                                   float* __restrict__ ctx,
                                                   float* __restrict__ gvec) {
  const int bh = blockIdx.x, b = bh >> 4, h = bh & 15;
  const int lane = threadIdx.x;
  float pm[8];
  float m = -1e30f;
#pragma unroll
  for (int c = 0; c < 8; ++c) { pm[c] = P[bh * 8 + c]; m = fmaxf(m, pm[c]); }
  float tot = 0.f, g = 0.f;
#pragma unroll
  for (int c = 0; c < 8; ++c) {
    float e = __expf(pm[c] - m);
    tot += P[512 + bh * 8 + c] * e;
    g += P[1024 + (bh * 8 + c) * 64 + lane] * e;
  }
  g /= tot;
  gvec[b * HID + h * HDIM + lane] = g;
  ctx[(size_t)b * SS * HID + h * HDIM + lane] = g;
}

// ------------------------------------------------- local attention (4 keys/pos)
__device__ __forceinline__ void unpack16(const ushort* __restrict__ p, float* f) {
  uint4 v0 = *(const uint4*)p;
  uint4 v1 = *(const uint4*)(p + 8);
  unsigned u[8] = {v0.x, v0.y, v0.z, v0.w, v1.x, v1.y, v1.z, v1.w};
#pragma unroll
  for (int i = 0; i < 8; ++i) {
    f[2*i]   = __uint_as_float(u[i] << 16);
    f[2*i+1] = __uint_as_float(u[i] & 0xffff0000u);
  }
}

__global__ __launch_bounds__(256) void local_attn_k(const ushort* __restrict__ QK,
                                                    const float* __restrict__ gvec,
                                                    float* __restrict__ out) {
  const int blk = blockIdx.x;
  const int b = blk >> 10;
  const int s = 1 + ((blk & 1023) << 2) + (int)(threadIdx.x >> 6);
  if (s >= SS) return;
  const int lane = threadIdx.x & 63;
  const int g = lane >> 2, j = lane & 3;
  const int db = g*HDIM + j*16;

  const size_t base = ((size_t)b*SS + s) * NN;
  const ushort* qp  = QK + base + db;
  const ushort* ksp = QK + base + HID + db;
  const ushort* kpp = QK + base - NN + HID + db;
  const int sn = (s == SS-1) ? 0 : s + 1;
  const ushort* knp = QK + ((size_t)b*SS + sn)*NN + HID + db;
  const float*  gvp = gvec + b*HID + db;

  float q[16], ks[16], kp[16], kn[16], gv[16];
  unpack16(qp, q); unpack16(ksp, ks); unpack16(kpp, kp); unpack16(knp, kn);
#pragma unroll
  for (int t = 0; t < 16; t += 4) *(float4*)(gv + t) = *(const float4*)(gvp + t);

  float d0=0.f, d1=0.f, d2=0.f, d3=0.f;
#pragma unroll
  for (int t = 0; t < 16; ++t) {
    d0 += q[t]*ks[t]; d1 += q[t]*gv[t]; d2 += q[t]*kp[t]; d3 += q[t]*kn[t];
  }
  d0 += __shfl_xor(d0, 1, 64); d0 += __shfl_xor(d0, 2, 64);
  d1 += __shfl_xor(d1, 1, 64); d1 += __shfl_xor(d1, 2, 64);
  d2 += __shfl_xor(d2, 1, 64); d2 += __shfl_xor(d2, 2, 64);
  d3 += __shfl_xor(d3, 1, 64); d3 += __shfl_xor(d3, 2, 64);

  float s0 = d0*0.125f, s1 = d1*0.125f, s2 = d2*0.125f, s3 = d3*0.125f;
  float m = fmaxf(fmaxf(s0, s1), fmaxf(s2, s3));
  float e0 = __expf(s0 - m), e1 = __expf(s1 - m), e2 = __expf(s2 - m), e3 = __expf(s3 - m);
  float inv = 1.f / (e0 + e1 + e2 + e3);
  float a0 = e0*inv, a1 = e1*inv, a2 = e2*inv, a3 = e3*inv;

  float o[16];
#pragma unroll
  for (int t = 0; t < 16; ++t) o[t] = a0*ks[t] + a1*gv[t] + a2*kp[t] + a3*kn[t];
  float* cp = out + ((size_t)b*SS + s)*HID + db;
#pragma unroll
  for (int t = 0; t < 16; t += 4) *(float4*)(cp + t) = *(const float4*)(o + t);

  if (j == 0) {
    float4 av; av.x = a0; av.y = a1; av.z = a2; av.w = a3;
    *(float4*)(out + (size_t)BB*SS*HID + (((size_t)b*NHEADS + g)*(SS-1) + (s-1))*4) = av;
  }
}

// ---------------------------------------------------------------------- launch
extern "C" void kernel_launch(void* const* d_in, const int* in_sizes, int n_in,
                              void* d_out, int out_size, void* d_ws, size_t ws_size,
                              hipStream_t stream) {
  const float* hs   = (const float*)d_in[0];
  const float* mask = (const float*)d_in[1];
  const float* Wq   = (const float*)d_in[2];
  const float* bq   = (const float*)d_in[3];
  const float* Wkv  = (const float*)d_in[4];
  const float* bkv  = (const float*)d_in[5];
  float* out = (float*)d_out;

  char* ws = (char*)d_ws;
  ushort* hsb  = (ushort*)ws;                                   // 32 MB
  ushort* Bt   = (ushort*)(ws + 33554432);                      // 4 MB
  ushort* QK   = (ushort*)(ws + 33554432 + 4194304);            // 64 MB
  float*  gvec = (float*)(ws + 33554432 + 4194304 + 67108864);  // 16 KB
  float*  P    = (float*)(ws + 33554432 + 4194304 + 67108864 + 16384);  // ~140 KB

  cast_hs_k<<<MM*KK/(256*8), 256, 0, stream>>>(hs, hsb);
  wcast_k<<<dim3(KK/32, NN/32), dim3(32, 8), 0, stream>>>(Wq, Wkv, Bt);

  // ---- diagnostic ablations (scratch into QK; overwritten by gemm_k below)
  gemm_abl<0, 1, 5><<<256, 512, 131072, stream>>>(hsb, Bt, QK);  // no ds_reads
  gemm_abl<1, 1, 8><<<256, 512, 131072, stream>>>(hsb, Bt, QK);  // barrier+MFMA floor

  gemm_k<<<dim3((MM/256)*(NN/256)), dim3(512), 131072, stream>>>(hsb, Bt, bq, bkv, QK);
  gattn_part_k<<<BB*NHEADS*GCH, 512, 0, stream>>>(QK, mask, P);
  gattn_comb_k<<<BB*NHEADS, 64, 0, stream>>>(P, out, gvec);
  local_attn_k<<<BB*1024, 256, 0, stream>>>(QK, gvec, out);
}

// Round 9
// 178.170 us; speedup vs baseline: 2.5742x; 2.5742x over previous
//
#include <hip/hip_runtime.h>
#include <hip/hip_bf16.h>

#define NHEADS 16
#define HDIM   64
#define HID    1024
#define BB     4
#define SS     4096
#define MM     (BB*SS)      // 16384 rows
#define KK     HID          // 1024
#define NN     (2*HID)      // 2048 cols (Q | K)

using short8 = __attribute__((ext_vector_type(8))) short;
using f32x4  = __attribute__((ext_vector_type(4))) float;

__device__ __forceinline__ float bf2f(ushort u) {
  return __uint_as_float(((unsigned)u) << 16);
}
__device__ __forceinline__ ushort f2bf(float f) {
  unsigned u = __float_as_uint(f);
  unsigned r = (u + 0x7fffu + ((u >> 16) & 1u)) >> 16;  // RNE
  return (ushort)r;
}

// -------------------------------------------- hs -> Af (MFMA-fragment layout)
// Af[mt][g][lane][8]: mt=row/16 (0..1023), g=k/32 (0..31), lane=(hi*16+lr),
// element (lane,e) = hs[mt*16+lr][g*32+hi*8+e].  Each fragment = 1KB contiguous.
__global__ __launch_bounds__(256) void af_cast_k(const float* __restrict__ hs,
                                                 ushort* __restrict__ Af) {
  const int t = threadIdx.x;
  const int U = blockIdx.x * 4 + (t >> 6);      // unit = (mt,g)
  const int l = t & 63, lr = l & 15, hi = l >> 4;
  const int mt = U >> 5, g = U & 31;
  const float* src = hs + (size_t)(mt * 16 + lr) * HID + g * 32 + hi * 8;
  float4 x = *(const float4*)src;
  float4 y = *(const float4*)(src + 4);
  ushort r[8];
  r[0]=f2bf(x.x); r[1]=f2bf(x.y); r[2]=f2bf(x.z); r[3]=f2bf(x.w);
  r[4]=f2bf(y.x); r[5]=f2bf(y.y); r[6]=f2bf(y.z); r[7]=f2bf(y.w);
  *(uint4*)(Af + (size_t)U * 512 + l * 8) = *(const uint4*)r;
}

// ------------------------------- W (K,N) -> Bf (MFMA-fragment layout), Wq|Wkv
// Bf[nt][g][lane][8]: element = W[g*32+hi*8+e][nt*16+lr]  (transposed via LDS)
__global__ __launch_bounds__(256) void wf_cast_k(const float* __restrict__ Wq,
                                                 const float* __restrict__ Wkv,
                                                 ushort* __restrict__ Bf) {
  __shared__ float tile[32][33];
  const int k0 = blockIdx.x * 32, n0 = blockIdx.y * 32;
  const int tx = threadIdx.x & 31, ty = threadIdx.x >> 5;
  const float* src = (n0 < HID) ? Wq : Wkv;
  const int nc = (n0 < HID) ? n0 : n0 - HID;
#pragma unroll
  for (int j = 0; j < 4; ++j)
    tile[ty + 8*j][tx] = src[(size_t)(k0 + ty + 8*j) * HID + nc + tx];
  __syncthreads();
  const int t = threadIdx.x;
  if (t < 128) {
    const int l = t & 63, h = t >> 6, lr = l & 15, hi = l >> 4;
    const int nt = (n0 >> 4) + h, g = k0 >> 5;
    ushort r[8];
#pragma unroll
    for (int e = 0; e < 8; ++e) r[e] = f2bf(tile[hi*8 + e][h*16 + lr]);
    *(uint4*)(Bf + (size_t)(nt * 32 + g) * 512 + l * 8) = *(const uint4*)r;
  }
}

// ---------------------------------------------------------------- fused QK GEMM
// All-register streaming GEMM: operands pre-fragmented in global memory (Af/Bf),
// fragments load global->VGPR directly (coalesced 1KB per instruction).
// NO LDS, NO barriers, NO staging. 256x256 tile, 8 waves (2Mx4N), wave tile
// 128x64, K-loop over 32 groups of K=32, 2-deep ping-pong prefetch (compiler
// inserts counted vmcnt). Rationale: R8 ablation showed ds_read path = +738
// cyc/phase (46% of phase time) on top of a 620-cyc MFMA floor; removing LDS
// removes that term plus barrier (+152) and staging (+102) terms.
__global__ __launch_bounds__(512, 2) void gemm_k(const ushort* __restrict__ Af,
                                                 const ushort* __restrict__ Bf,
                                                 const float* __restrict__ bq,
                                                 const float* __restrict__ bkv,
                                                 ushort* __restrict__ C) {
  const int tid = threadIdx.x, bid = blockIdx.x;
  const int wg = (bid & 7) * 64 + (bid >> 3);   // XCD swizzle (512 % 8 == 0)
  const int tm = wg >> 3, tn = wg & 7;
  const int w = tid >> 6, lane = tid & 63;
  const int wr = w >> 2, wc = w & 3;
  const int lr = lane & 15, hi = lane >> 4;

  // fragment base pointers (ushort units); frag (m,g) at aB + m*16384 + g*512
  const ushort* aB = Af + (size_t)(tm * 16 + wr * 8) * 16384 + lane * 8;
  const ushort* bB = Bf + (size_t)(tn * 16 + wc * 4) * 16384 + lane * 8;

  f32x4 acc[8][4];
#pragma unroll
  for (int M = 0; M < 8; ++M)
#pragma unroll
    for (int n = 0; n < 4; ++n) acc[M][n] = (f32x4){0.f, 0.f, 0.f, 0.f};

  short8 a0[8], a1[8], b0[4], b1[4];

#define LDA(SET, G)                                                             \
  _Pragma("unroll") for (int m = 0; m < 8; ++m)                                 \
    SET[m] = *(const short8*)(aB + m * 16384 + (G) * 512);
#define LDB(SET, G)                                                             \
  _Pragma("unroll") for (int n = 0; n < 4; ++n)                                 \
    SET[n] = *(const short8*)(bB + n * 16384 + (G) * 512);
#define MFM(AS, BS)                                                             \
  _Pragma("unroll") for (int m = 0; m < 8; ++m)                                 \
    _Pragma("unroll") for (int n = 0; n < 4; ++n)                               \
      acc[m][n] = __builtin_amdgcn_mfma_f32_16x16x32_bf16(BS[n], AS[m],         \
                                                          acc[m][n], 0, 0, 0);

  LDA(a0, 0) LDB(b0, 0)
  LDA(a1, 1) LDB(b1, 1)

#pragma unroll 1
  for (int g = 0; g < 32; g += 2) {
    MFM(a0, b0)
    LDA(a0, g + 2) LDB(b0, g + 2)   // prefetch (g=30 tail reads harmless junk)
    MFM(a1, b1)
    LDA(a1, g + 3) LDB(b1, g + 3)
  }

#undef MFM
#undef LDB
#undef LDA

  // ---- epilogue: lane holds C[row = wr*128+M*16+lr][col = wc*64+n*16+hi*4+t]
  const float* bias = (tn < 4) ? (bq + tn * 256) : (bkv + (tn - 4) * 256);
  float4 bv[4];
#pragma unroll
  for (int n = 0; n < 4; ++n)
    bv[n] = *(const float4*)(bias + wc * 64 + n * 16 + hi * 4);

#pragma unroll
  for (int M = 0; M < 8; ++M) {
    size_t row = (size_t)tm * 256 + wr * 128 + M * 16 + lr;
    ushort* cp = C + row * NN + tn * 256 + wc * 64 + hi * 4;
#pragma unroll
    for (int n = 0; n < 4; ++n) {
      unsigned p0 = (unsigned)f2bf(acc[M][n][0] + bv[n].x) |
                    ((unsigned)f2bf(acc[M][n][1] + bv[n].y) << 16);
      unsigned p1 = (unsigned)f2bf(acc[M][n][2] + bv[n].z) |
                    ((unsigned)f2bf(acc[M][n][3] + bv[n].w) << 16);
      uint2 st; st.x = p0; st.y = p1;
      *(uint2*)(cp + n * 16) = st;
    }
  }
}

// ------------------------------------------------- global attention, split-K flash
#define GCH 8
#define GCS (SS / GCH)  // 512

__global__ __launch_bounds__(512) void gattn_part_k(const ushort* __restrict__ QK,
                                                    const float* __restrict__ mask,
                                                    float* __restrict__ P) {
  const int bh = blockIdx.x >> 3, c = blockIdx.x & 7;
  const int b = bh >> 4, h = bh & 15;
  const int tid = threadIdx.x, w = tid >> 6, lane = tid & 63;
  __shared__ float sc[GCS];
  __shared__ float red[8];
  __shared__ float vacc[8][64];

  const float gq = bf2f(QK[(size_t)b * SS * NN + h * HDIM + lane]);  // Q row s=0
  const int s0 = c * GCS;
  float mx = -1e30f;
  for (int s = w; s < GCS; s += 8) {
    float kv = bf2f(QK[((size_t)b * SS + s0 + s) * NN + HID + h * HDIM + lane]);
    float p = gq * kv;
#pragma unroll
    for (int o = 32; o; o >>= 1) p += __shfl_xor(p, o, 64);
    p = p * 0.125f + mask[b * SS + s0 + s];
    if (lane == 0) sc[s] = p;
    mx = fmaxf(mx, p);
  }
  if (lane == 0) red[w] = mx;
  __syncthreads();
  float bm = -1e30f;
#pragma unroll
  for (int i = 0; i < 8; ++i) bm = fmaxf(bm, red[i]);
  __syncthreads();
  float ls = 0.f;
  for (int s = tid; s < GCS; s += 512) {
    float e = __expf(sc[s] - bm);
    sc[s] = e;
    ls += e;
  }
#pragma unroll
  for (int o = 32; o; o >>= 1) ls += __shfl_xor(ls, o, 64);
  if (lane == 0) red[w] = ls;
  __syncthreads();
  float tot = 0.f;
#pragma unroll
  for (int i = 0; i < 8; ++i) tot += red[i];

  float a = 0.f;
  for (int s = w; s < GCS; s += 8)
    a += sc[s] * bf2f(QK[((size_t)b * SS + s0 + s) * NN + HID + h * HDIM + lane]);
  vacc[w][lane] = a;
  __syncthreads();
  if (w == 0) {
    float v = 0.f;
#pragma unroll
    for (int i = 0; i < 8; ++i) v += vacc[i][lane];
    P[1024 + (bh * 8 + c) * 64 + lane] = v;
    if (lane == 0) {
      P[bh * 8 + c] = bm;
      P[512 + bh * 8 + c] = tot;
    }
  }
}

__global__ __launch_bounds__(64) void gattn_comb_k(const float* __restrict__ P,
                                                   float* __restrict__ ctx,
                                                   float* __restrict__ gvec) {
  const int bh = blockIdx.x, b = bh >> 4, h = bh & 15;
  const int lane = threadIdx.x;
  float pm[8];
  float m = -1e30f;
#pragma unroll
  for (int c = 0; c < 8; ++c) { pm[c] = P[bh * 8 + c]; m = fmaxf(m, pm[c]); }
  float tot = 0.f, g = 0.f;
#pragma unroll
  for (int c = 0; c < 8; ++c) {
    float e = __expf(pm[c] - m);
    tot += P[512 + bh * 8 + c] * e;
    g += P[1024 + (bh * 8 + c) * 64 + lane] * e;
  }
  g /= tot;
  gvec[b * HID + h * HDIM + lane] = g;
  ctx[(size_t)b * SS * HID + h * HDIM + lane] = g;
}

// ------------------------------------------------- local attention (4 keys/pos)
__device__ __forceinline__ void unpack16(const ushort* __restrict__ p, float* f) {
  uint4 v0 = *(const uint4*)p;
  uint4 v1 = *(const uint4*)(p + 8);
  unsigned u[8] = {v0.x, v0.y, v0.z, v0.w, v1.x, v1.y, v1.z, v1.w};
#pragma unroll
  for (int i = 0; i < 8; ++i) {
    f[2*i]   = __uint_as_float(u[i] << 16);
    f[2*i+1] = __uint_as_float(u[i] & 0xffff0000u);
  }
}

__global__ __launch_bounds__(256) void local_attn_k(const ushort* __restrict__ QK,
                                                    const float* __restrict__ gvec,
                                                    float* __restrict__ out) {
  const int blk = blockIdx.x;
  const int b = blk >> 10;
  const int s = 1 + ((blk & 1023) << 2) + (int)(threadIdx.x >> 6);
  if (s >= SS) return;
  const int lane = threadIdx.x & 63;
  const int g = lane >> 2, j = lane & 3;
  const int db = g*HDIM + j*16;

  const size_t base = ((size_t)b*SS + s) * NN;
  const ushort* qp  = QK + base + db;
  const ushort* ksp = QK + base + HID + db;
  const ushort* kpp = QK + base - NN + HID + db;
  const int sn = (s == SS-1) ? 0 : s + 1;
  const ushort* knp = QK + ((size_t)b*SS + sn)*NN + HID + db;
  const float*  gvp = gvec + b*HID + db;

  float q[16], ks[16], kp[16], kn[16], gv[16];
  unpack16(qp, q); unpack16(ksp, ks); unpack16(kpp, kp); unpack16(knp, kn);
#pragma unroll
  for (int t = 0; t < 16; t += 4) *(float4*)(gv + t) = *(const float4*)(gvp + t);

  float d0=0.f, d1=0.f, d2=0.f, d3=0.f;
#pragma unroll
  for (int t = 0; t < 16; ++t) {
    d0 += q[t]*ks[t]; d1 += q[t]*gv[t]; d2 += q[t]*kp[t]; d3 += q[t]*kn[t];
  }
  d0 += __shfl_xor(d0, 1, 64); d0 += __shfl_xor(d0, 2, 64);
  d1 += __shfl_xor(d1, 1, 64); d1 += __shfl_xor(d1, 2, 64);
  d2 += __shfl_xor(d2, 1, 64); d2 += __shfl_xor(d2, 2, 64);
  d3 += __shfl_xor(d3, 1, 64); d3 += __shfl_xor(d3, 2, 64);

  float s0 = d0*0.125f, s1 = d1*0.125f, s2 = d2*0.125f, s3 = d3*0.125f;
  float m = fmaxf(fmaxf(s0, s1), fmaxf(s2, s3));
  float e0 = __expf(s0 - m), e1 = __expf(s1 - m), e2 = __expf(s2 - m), e3 = __expf(s3 - m);
  float inv = 1.f / (e0 + e1 + e2 + e3);
  float a0 = e0*inv, a1 = e1*inv, a2 = e2*inv, a3 = e3*inv;

  float o[16];
#pragma unroll
  for (int t = 0; t < 16; ++t) o[t] = a0*ks[t] + a1*gv[t] + a2*kp[t] + a3*kn[t];
  float* cp = out + ((size_t)b*SS + s)*HID + db;
#pragma unroll
  for (int t = 0; t < 16; t += 4) *(float4*)(cp + t) = *(const float4*)(o + t);

  if (j == 0) {
    float4 av; av.x = a0; av.y = a1; av.z = a2; av.w = a3;
    *(float4*)(out + (size_t)BB*SS*HID + (((size_t)b*NHEADS + g)*(SS-1) + (s-1))*4) = av;
  }
}

// ---------------------------------------------------------------------- launch
extern "C" void kernel_launch(void* const* d_in, const int* in_sizes, int n_in,
                              void* d_out, int out_size, void* d_ws, size_t ws_size,
                              hipStream_t stream) {
  const float* hs   = (const float*)d_in[0];
  const float* mask = (const float*)d_in[1];
  const float* Wq   = (const float*)d_in[2];
  const float* bq   = (const float*)d_in[3];
  const float* Wkv  = (const float*)d_in[4];
  const float* bkv  = (const float*)d_in[5];
  float* out = (float*)d_out;

  char* ws = (char*)d_ws;
  ushort* Af   = (ushort*)ws;                                   // 32 MB (frag layout)
  ushort* Bf   = (ushort*)(ws + 33554432);                      // 4 MB  (frag layout)
  ushort* QK   = (ushort*)(ws + 33554432 + 4194304);            // 64 MB
  float*  gvec = (float*)(ws + 33554432 + 4194304 + 67108864);  // 16 KB
  float*  P    = (float*)(ws + 33554432 + 4194304 + 67108864 + 16384);  // ~140 KB

  af_cast_k<<<8192, 256, 0, stream>>>(hs, Af);
  wf_cast_k<<<dim3(KK/32, NN/32), 256, 0, stream>>>(Wq, Wkv, Bf);
  gemm_k<<<512, 512, 0, stream>>>(Af, Bf, bq, bkv, QK);
  gattn_part_k<<<BB*NHEADS*GCH, 512, 0, stream>>>(QK, mask, P);
  gattn_comb_k<<<BB*NHEADS, 64, 0, stream>>>(P, out, gvec);
  local_attn_k<<<BB*1024, 256, 0, stream>>>(QK, gvec, out);
}